// Round 19
// baseline (33.199 us; speedup 1.0000x reference)
//
#include <hip/hip_runtime.h>
#include <hip/hip_fp16.h>

// KA-conv: out[b,o,h,w] = sum_m P_om(v) / (1+|Q_om(v)|), v = zero-padded patch
// value, m = c*9+ki*3+kj, M=144. ~75.5M rational evals.
//
// R19 (= R18 resubmit; infra failure, never ran). Single-variable vs R17
// (best=31.6us): prep now emits VERTICAL-PAIR half2 planes: vp[r][col] =
// pack(half(pad[r][col]), half(pad[r+1][col])). Main-loop per c-iter: 15 u32
// loads replace 18 f32 loads + 15 v_cvt_pk — the loaded word IS the packed
// Horner operand (pair h{k,k+1} = vp[h0+k], k=0..4). Everything else frozen
// at R17: 4 c-quarter waves x 64 cols, thread = 4 rows x 4 channels, f16-pk
// dual-chain TAP4, broadcast-f16 coefficient records via s_load
// (readfirstlane-uniform o and q), 4KB LDS cross-quarter reduce, grid 2048,
// launch_bounds(256,4).

constexpr int Bn = 4, Cin = 16, Hh = 64, Ww = 64, Oc = 32, Mtot = 144;
constexpr int PW = 66;                        // padded plane width
constexpr int VR = 65;                        // vpair rows (pairs r,r+1; r=0..64)
constexpr int PLANE = VR * PW;                // 4290 u32 per plane
constexpr size_t WSVP_U32 = (size_t)Bn * Cin * PLANE;   // 274560
constexpr int NREC = Oc * Mtot;               // 4608 coefficient records

// ---- prep: vertical-pair half2 planes + broadcast-f16 coeff records ----
__global__ __launch_bounds__(256)
void ka_prep_kernel(const float* __restrict__ x,
                    const float* __restrict__ nums,
                    const float* __restrict__ denoms,
                    unsigned int* __restrict__ wsu) {
  const int blk = blockIdx.x;
  if (blk < Bn * Cin) {
    const float* __restrict__ xp = x + (size_t)blk * Hh * Ww;
    unsigned int* __restrict__ vp = wsu + (size_t)blk * PLANE;
    for (int i = threadIdx.x; i < PLANE; i += 256) {
      const int r = i / PW, col = i % PW;
      // padded value at (rr, col): rr,col in padded coords (66x66)
      const bool i0 = (r >= 1) & (r <= Hh) & (col >= 1) & (col <= Ww);
      const bool i1 = (r + 1 >= 1) & (r + 1 <= Hh) & (col >= 1) & (col <= Ww);
      const float p0 = i0 ? xp[(r - 1) * Ww + (col - 1)] : 0.f;
      const float p1 = i1 ? xp[r * Ww + (col - 1)] : 0.f;
      const unsigned short h0 = __half_as_ushort(__float2half_rn(p0));
      const unsigned short h1 = __half_as_ushort(__float2half_rn(p1));
      vp[i] = ((unsigned int)h1 << 16) | h0;   // low = row r, high = row r+1
    }
  } else {
    // 12 u32s per record = [A0..A5, C1..C4, pad, pad], each u32 = (h<<16)|h
    const int idx = (blk - Bn * Cin) * 256 + threadIdx.x;
    if (idx < NREC) {
      const float* __restrict__ a = nums + (size_t)idx * 6;
      const float* __restrict__ c = denoms + (size_t)idx * 4;
      unsigned int* __restrict__ r = wsu + WSVP_U32 + (size_t)idx * 12;
      #pragma unroll
      for (int k = 0; k < 6; ++k) {
        const unsigned short h = __half_as_ushort(__float2half_rn(a[k]));
        r[k] = ((unsigned int)h << 16) | h;
      }
      #pragma unroll
      for (int k = 0; k < 4; ++k) {
        const unsigned short h = __half_as_ushort(__float2half_rn(c[k]));
        r[6 + k] = ((unsigned int)h << 16) | h;
      }
      r[10] = 0u; r[11] = 0u;
    }
  }
}

__device__ __forceinline__ __half2 u2h2(unsigned int u) {
  union { unsigned int u; __half2 h; } cv; cv.u = u; return cv.h;
}

__global__ __launch_bounds__(256, 4)
void ka_conv_kernel(const unsigned int* __restrict__ wsu,
                    float* __restrict__ out) {
  __shared__ float part[1024];            // [quarter][row0..3][w]

  const int tid = threadIdx.x;
  const int n   = blockIdx.x;
  const int ht  = n & 15;                 // 16 tiles of 4 rows (low bits)
  const int o   = __builtin_amdgcn_readfirstlane((n >> 4) & 31);  // uniform
  const int b   = n >> 9;                 // batch

  const int w  = tid & 63;                // lane == output column
  const int q  = __builtin_amdgcn_readfirstlane(tid >> 6);   // c-quarter 0..3
  const int h0 = ht * 4;                  // block's 4 output rows

  const unsigned int* __restrict__ xb = wsu + (size_t)b * Cin * PLANE;
  const unsigned int* __restrict__ coef = wsu + WSVP_U32 + (size_t)o * Mtot * 12;

  // 6 accumulators: column (3) x row-pair (A: rows h0,h0+1; B: h0+2,h0+3)
  __half2 a0A = __floats2half2_rn(0.f, 0.f);
  __half2 a1A = a0A, a2A = a0A, a0B = a0A, a1B = a0A, a2B = a0A;
  const __half2 one2 = __floats2half2_rn(1.f, 1.f);

  // one tap slot t: 4 evals as two packed Horner chains (ILP 2).
  // rr[k] = wave-uniform s_load -> single-SGPR operand of each v_pk_fma_f16.
#define TAP4(t, vA, vB, accA, accB) do {                                       \
    const unsigned int* __restrict__ rr = pc + (t) * 12;                       \
    __half2 nA = __hfma2(u2h2(rr[5]), (vA), u2h2(rr[4]));                      \
    __half2 nB = __hfma2(u2h2(rr[5]), (vB), u2h2(rr[4]));                      \
    nA = __hfma2(nA, (vA), u2h2(rr[3]));  nB = __hfma2(nB, (vB), u2h2(rr[3])); \
    nA = __hfma2(nA, (vA), u2h2(rr[2]));  nB = __hfma2(nB, (vB), u2h2(rr[2])); \
    nA = __hfma2(nA, (vA), u2h2(rr[1]));  nB = __hfma2(nB, (vB), u2h2(rr[1])); \
    nA = __hfma2(nA, (vA), u2h2(rr[0]));  nB = __hfma2(nB, (vB), u2h2(rr[0])); \
    __half2 dA = __hfma2(u2h2(rr[9]), (vA), u2h2(rr[8]));                      \
    __half2 dB = __hfma2(u2h2(rr[9]), (vB), u2h2(rr[8]));                      \
    dA = __hfma2(dA, (vA), u2h2(rr[7]));  dB = __hfma2(dB, (vB), u2h2(rr[7])); \
    dA = __hfma2(dA, (vA), u2h2(rr[6]));  dB = __hfma2(dB, (vB), u2h2(rr[6])); \
    dA = __hmul2(dA, (vA));               dB = __hmul2(dB, (vB));              \
    const __half2 eA = __hadd2(one2, __habs2(dA));                             \
    const __half2 eB = __hadd2(one2, __habs2(dB));                             \
    accA = __hfma2(nA, h2rcp(eA), accA);                                       \
    accB = __hfma2(nB, h2rcp(eB), accB);                                       \
  } while (0)

  #pragma unroll 2
  for (int ci = 0; ci < 4; ++ci) {
    const int c = q * 4 + ci;              // uniform (q is SGPR)
    const unsigned int* __restrict__ xc = xb + (size_t)c * PLANE;
    const int base = h0 * PW + w;          // vpair row h0, padded col w

    // 15 u32 loads = packed pairs L[k][j] = (pad[h0+k], pad[h0+k+1]) at col w+j
    const __half2 L0j0 = u2h2(xc[base + 0 * PW + 0]);
    const __half2 L0j1 = u2h2(xc[base + 0 * PW + 1]);
    const __half2 L0j2 = u2h2(xc[base + 0 * PW + 2]);
    const __half2 L1j0 = u2h2(xc[base + 1 * PW + 0]);
    const __half2 L1j1 = u2h2(xc[base + 1 * PW + 1]);
    const __half2 L1j2 = u2h2(xc[base + 1 * PW + 2]);
    const __half2 L2j0 = u2h2(xc[base + 2 * PW + 0]);
    const __half2 L2j1 = u2h2(xc[base + 2 * PW + 1]);
    const __half2 L2j2 = u2h2(xc[base + 2 * PW + 2]);
    const __half2 L3j0 = u2h2(xc[base + 3 * PW + 0]);
    const __half2 L3j1 = u2h2(xc[base + 3 * PW + 1]);
    const __half2 L3j2 = u2h2(xc[base + 3 * PW + 2]);
    const __half2 L4j0 = u2h2(xc[base + 4 * PW + 0]);
    const __half2 L4j1 = u2h2(xc[base + 4 * PW + 1]);
    const __half2 L4j2 = u2h2(xc[base + 4 * PW + 2]);

    const unsigned int* __restrict__ pc = coef + (size_t)c * 9 * 12;  // SGPR
    // tap t = ki*3 + j: pair A = L[ki][j] (rows h0,h0+1), B = L[ki+2][j]
    TAP4(0, L0j0, L2j0, a0A, a0B);
    TAP4(1, L0j1, L2j1, a1A, a1B);
    TAP4(2, L0j2, L2j2, a2A, a2B);
    TAP4(3, L1j0, L3j0, a0A, a0B);
    TAP4(4, L1j1, L3j1, a1A, a1B);
    TAP4(5, L1j2, L3j2, a2A, a2B);
    TAP4(6, L2j0, L4j0, a0A, a0B);
    TAP4(7, L2j1, L4j1, a1A, a1B);
    TAP4(8, L2j2, L4j2, a2A, a2B);
  }
#undef TAP4

  // per-thread column sum -> f32, stash in LDS: part[q][row][w]
  const float2 fA = __half22float2(__hadd2(__hadd2(a0A, a1A), a2A));
  const float2 fB = __half22float2(__hadd2(__hadd2(a0B, a1B), a2B));
  part[q * 256 +   0 + w] = fA.x;   // row h0+0
  part[q * 256 +  64 + w] = fA.y;   // row h0+1
  part[q * 256 + 128 + w] = fB.x;   // row h0+2
  part[q * 256 + 192 + w] = fB.y;   // row h0+3
  __syncthreads();

  // finalize: fixed-order cross-quarter add (deterministic)
  {
    const int row = tid >> 6, ww = tid & 63;
    const int s = row * 64 + ww;
    const float v = ((part[s] + part[256 + s]) + part[512 + s]) + part[768 + s];
    out[((size_t)(b * Oc + o) * Hh + h0 + row) * Ww + ww] = v;
  }
}

extern "C" void kernel_launch(void* const* d_in, const int* in_sizes, int n_in,
                              void* d_out, int out_size, void* d_ws, size_t ws_size,
                              hipStream_t stream) {
  const float* x      = (const float*)d_in[0];
  const float* nums   = (const float*)d_in[1];
  const float* denoms = (const float*)d_in[2];
  float* out          = (float*)d_out;
  unsigned int* wsu   = (unsigned int*)d_ws;

  const int padBlocks = Bn * Cin;
  const int recBlocks = (NREC + 255) / 256;
  ka_prep_kernel<<<padBlocks + recBlocks, 256, 0, stream>>>(x, nums, denoms, wsu);

  // main: blockIdx = ((b*32 + o)*16 + ht), ht in low bits
  ka_conv_kernel<<<Bn * Oc * 16, 256, 0, stream>>>(wsu, out);
}

// Round 20
// 31.951 us; speedup vs baseline: 1.0391x; 1.0391x over previous
//
#include <hip/hip_runtime.h>
#include <hip/hip_fp16.h>

// KA-conv: out[b,o,h,w] = sum_m P_om(v) / (1+|Q_om(v)|), v = zero-padded patch
// value, m = c*9+ki*3+kj, M=144. ~75.5M rational evals.
//
// R20 = R17 verbatim (best measured: 31.6us), locking in the session best.
// R19's vertical-pair variant (33.2us) reverted. Structure: 256-thr block =
// 4 c-quarter waves x 64 cols; thread = 4 output rows x 4 channels; f16-pk
// dual Horner chains (TAP4, 4 evals per coefficient fetch); padded-x f32
// planes + broadcast-f16 coefficient records in ws (s_load via
// readfirstlane-uniform o and q); 4KB LDS cross-quarter reduce; grid 2048
// (8 blocks/CU at VGPR<=64); launch_bounds(256,4).
// Session floor evidence: 9 consecutive structural variants within 31.6-34.3us
// (busy ~15us incl. quarter-rate rcp; ~10us launch/short-kernel overhead;
// residual latency gaps insensitive to occupancy/ILP/precision).

constexpr int Bn = 4, Cin = 16, Hh = 64, Ww = 64, Oc = 32, Mtot = 144;
constexpr int PW = 66;                       // padded plane width/height
constexpr size_t WSX_FLOATS = (size_t)Bn * Cin * PW * PW;   // 278784
constexpr int NREC = Oc * Mtot;              // 4608 coefficient records

// ---- prep: pad x planes (f32) + broadcast-f16 coefficient records ----
__global__ __launch_bounds__(256)
void ka_prep_kernel(const float* __restrict__ x,
                    const float* __restrict__ nums,
                    const float* __restrict__ denoms,
                    float* __restrict__ wsf) {
  const int blk = blockIdx.x;
  if (blk < Bn * Cin) {
    const float* __restrict__ xp = x + (size_t)blk * Hh * Ww;
    float* __restrict__ wp_ = wsf + (size_t)blk * PW * PW;
    for (int i = threadIdx.x; i < PW * PW; i += 256) {
      const int hp = i / PW, wq = i % PW;
      const bool in = (hp >= 1) & (hp <= Hh) & (wq >= 1) & (wq <= Ww);
      wp_[i] = in ? xp[(hp - 1) * Ww + (wq - 1)] : 0.f;
    }
  } else {
    // 12 u32s per record = [A0..A5, C1..C4, pad, pad], each u32 = (h<<16)|h
    const int idx = (blk - Bn * Cin) * 256 + threadIdx.x;
    if (idx < NREC) {
      const float* __restrict__ a = nums + (size_t)idx * 6;
      const float* __restrict__ c = denoms + (size_t)idx * 4;
      unsigned int* __restrict__ r =
          (unsigned int*)(wsf + WSX_FLOATS) + (size_t)idx * 12;
      #pragma unroll
      for (int k = 0; k < 6; ++k) {
        const unsigned short h = __half_as_ushort(__float2half_rn(a[k]));
        r[k] = ((unsigned int)h << 16) | h;
      }
      #pragma unroll
      for (int k = 0; k < 4; ++k) {
        const unsigned short h = __half_as_ushort(__float2half_rn(c[k]));
        r[6 + k] = ((unsigned int)h << 16) | h;
      }
      r[10] = 0u; r[11] = 0u;
    }
  }
}

__device__ __forceinline__ __half2 u2h2(unsigned int u) {
  union { unsigned int u; __half2 h; } cv; cv.u = u; return cv.h;
}

__global__ __launch_bounds__(256, 4)
void ka_conv_kernel(const float* __restrict__ wsf, float* __restrict__ out) {
  __shared__ float part[1024];            // [quarter][row0..3][w]

  const int tid = threadIdx.x;
  const int n   = blockIdx.x;
  const int ht  = n & 15;                 // 16 tiles of 4 rows (low bits)
  const int o   = __builtin_amdgcn_readfirstlane((n >> 4) & 31);  // uniform
  const int b   = n >> 9;                 // batch

  const int w  = tid & 63;                // lane == output column
  // q is wave-uniform at runtime; readfirstlane makes it PROVABLY uniform so
  // the coefficient address chain scalarizes to s_load (R16: SGPR=32 bug).
  const int q  = __builtin_amdgcn_readfirstlane(tid >> 6);   // c-quarter 0..3
  const int h0 = ht * 4;                  // block's 4 output rows

  const float* __restrict__ xb = wsf + (size_t)b * Cin * PW * PW;
  const unsigned int* __restrict__ coef =
      (const unsigned int*)(wsf + WSX_FLOATS) + (size_t)o * Mtot * 12;

  // 6 accumulators: per column (3) x row-pair (A: rows h0,h0+1; B: h0+2,h0+3)
  __half2 a0A = __floats2half2_rn(0.f, 0.f);
  __half2 a1A = a0A, a2A = a0A, a0B = a0A, a1B = a0A, a2B = a0A;
  const __half2 one2 = __floats2half2_rn(1.f, 1.f);

  // one tap slot t: 4 evals as two packed Horner chains (ILP 2).
  // rr[k] = wave-uniform s_load -> single-SGPR operand of each v_pk_fma_f16.
#define TAP4(t, vA, vB, accA, accB) do {                                       \
    const unsigned int* __restrict__ rr = pc + (t) * 12;                       \
    __half2 nA = __hfma2(u2h2(rr[5]), (vA), u2h2(rr[4]));                      \
    __half2 nB = __hfma2(u2h2(rr[5]), (vB), u2h2(rr[4]));                      \
    nA = __hfma2(nA, (vA), u2h2(rr[3]));  nB = __hfma2(nB, (vB), u2h2(rr[3])); \
    nA = __hfma2(nA, (vA), u2h2(rr[2]));  nB = __hfma2(nB, (vB), u2h2(rr[2])); \
    nA = __hfma2(nA, (vA), u2h2(rr[1]));  nB = __hfma2(nB, (vB), u2h2(rr[1])); \
    nA = __hfma2(nA, (vA), u2h2(rr[0]));  nB = __hfma2(nB, (vB), u2h2(rr[0])); \
    __half2 dA = __hfma2(u2h2(rr[9]), (vA), u2h2(rr[8]));                      \
    __half2 dB = __hfma2(u2h2(rr[9]), (vB), u2h2(rr[8]));                      \
    dA = __hfma2(dA, (vA), u2h2(rr[7]));  dB = __hfma2(dB, (vB), u2h2(rr[7])); \
    dA = __hfma2(dA, (vA), u2h2(rr[6]));  dB = __hfma2(dB, (vB), u2h2(rr[6])); \
    dA = __hmul2(dA, (vA));               dB = __hmul2(dB, (vB));              \
    const __half2 eA = __hadd2(one2, __habs2(dA));                             \
    const __half2 eB = __hadd2(one2, __habs2(dB));                             \
    accA = __hfma2(nA, h2rcp(eA), accA);                                       \
    accB = __hfma2(nB, h2rcp(eB), accB);                                       \
  } while (0)

  #pragma unroll 2
  for (int ci = 0; ci < 4; ++ci) {
    const int c = q * 4 + ci;              // uniform (q is SGPR)
    const float* __restrict__ xc = xb + (size_t)c * (PW * PW);
    const int base = h0 * PW + w;          // padded row h0, padded col w

    // 18 plain coalesced loads: padded rows h0..h0+5, padded cols w..w+2
    float x0j0 = xc[base + 0 * PW + 0], x0j1 = xc[base + 0 * PW + 1], x0j2 = xc[base + 0 * PW + 2];
    float x1j0 = xc[base + 1 * PW + 0], x1j1 = xc[base + 1 * PW + 1], x1j2 = xc[base + 1 * PW + 2];
    float x2j0 = xc[base + 2 * PW + 0], x2j1 = xc[base + 2 * PW + 1], x2j2 = xc[base + 2 * PW + 2];
    float x3j0 = xc[base + 3 * PW + 0], x3j1 = xc[base + 3 * PW + 1], x3j2 = xc[base + 3 * PW + 2];
    float x4j0 = xc[base + 4 * PW + 0], x4j1 = xc[base + 4 * PW + 1], x4j2 = xc[base + 4 * PW + 2];
    float x5j0 = xc[base + 5 * PW + 0], x5j1 = xc[base + 5 * PW + 1], x5j2 = xc[base + 5 * PW + 2];

    // packed row-pairs per column: h{k,k+1}[j]
    const __half2 h01j0 = __floats2half2_rn(x0j0, x1j0);
    const __half2 h01j1 = __floats2half2_rn(x0j1, x1j1);
    const __half2 h01j2 = __floats2half2_rn(x0j2, x1j2);
    const __half2 h12j0 = __floats2half2_rn(x1j0, x2j0);
    const __half2 h12j1 = __floats2half2_rn(x1j1, x2j1);
    const __half2 h12j2 = __floats2half2_rn(x1j2, x2j2);
    const __half2 h23j0 = __floats2half2_rn(x2j0, x3j0);
    const __half2 h23j1 = __floats2half2_rn(x2j1, x3j1);
    const __half2 h23j2 = __floats2half2_rn(x2j2, x3j2);
    const __half2 h34j0 = __floats2half2_rn(x3j0, x4j0);
    const __half2 h34j1 = __floats2half2_rn(x3j1, x4j1);
    const __half2 h34j2 = __floats2half2_rn(x3j2, x4j2);
    const __half2 h45j0 = __floats2half2_rn(x4j0, x5j0);
    const __half2 h45j1 = __floats2half2_rn(x4j1, x5j1);
    const __half2 h45j2 = __floats2half2_rn(x4j2, x5j2);

    const unsigned int* __restrict__ pc = coef + (size_t)c * 9 * 12;  // SGPR
    // tap t = ki*3 + j: pair A = h{ki,ki+1}[j], pair B = h{ki+2,ki+3}[j]
    TAP4(0, h01j0, h23j0, a0A, a0B);
    TAP4(1, h01j1, h23j1, a1A, a1B);
    TAP4(2, h01j2, h23j2, a2A, a2B);
    TAP4(3, h12j0, h34j0, a0A, a0B);
    TAP4(4, h12j1, h34j1, a1A, a1B);
    TAP4(5, h12j2, h34j2, a2A, a2B);
    TAP4(6, h23j0, h45j0, a0A, a0B);
    TAP4(7, h23j1, h45j1, a1A, a1B);
    TAP4(8, h23j2, h45j2, a2A, a2B);
  }
#undef TAP4

  // per-thread column sum -> f32, stash in LDS: part[q][row][w]
  const float2 fA = __half22float2(__hadd2(__hadd2(a0A, a1A), a2A));
  const float2 fB = __half22float2(__hadd2(__hadd2(a0B, a1B), a2B));
  part[q * 256 +   0 + w] = fA.x;   // row h0+0
  part[q * 256 +  64 + w] = fA.y;   // row h0+1
  part[q * 256 + 128 + w] = fB.x;   // row h0+2
  part[q * 256 + 192 + w] = fB.y;   // row h0+3
  __syncthreads();

  // finalize: fixed-order cross-quarter add (deterministic)
  {
    const int row = tid >> 6, ww = tid & 63;
    const int s = row * 64 + ww;
    const float v = ((part[s] + part[256 + s]) + part[512 + s]) + part[768 + s];
    out[((size_t)(b * Oc + o) * Hh + h0 + row) * Ww + ww] = v;
  }
}

extern "C" void kernel_launch(void* const* d_in, const int* in_sizes, int n_in,
                              void* d_out, int out_size, void* d_ws, size_t ws_size,
                              hipStream_t stream) {
  const float* x      = (const float*)d_in[0];
  const float* nums   = (const float*)d_in[1];
  const float* denoms = (const float*)d_in[2];
  float* out          = (float*)d_out;
  float* ws           = (float*)d_ws;

  const int padBlocks = Bn * Cin;
  const int recBlocks = (NREC + 255) / 256;
  ka_prep_kernel<<<padBlocks + recBlocks, 256, 0, stream>>>(x, nums, denoms, ws);

  // main: blockIdx = ((b*32 + o)*16 + ht), ht in low bits
  ka_conv_kernel<<<Bn * Oc * 16, 256, 0, stream>>>(ws, out);
}